// Round 7
// baseline (6208.151 us; speedup 1.0000x reference)
//
#include <hip/hip_runtime.h>
#include <hip/hip_bf16.h>

typedef __bf16 bf16x8 __attribute__((ext_vector_type(8)));
typedef float f32x4 __attribute__((ext_vector_type(4)));

__device__ __forceinline__ float b2f(ushort u){
  union { uint u; float f; } x; x.u = ((uint)u) << 16; return x.f;
}
__device__ __forceinline__ ushort f2b(float f){
  union { float f; uint u; } x; x.f = f;
  uint r = x.u + 0x7fff + ((x.u >> 16) & 1);
  return (ushort)(r >> 16);
}
__device__ __forceinline__ uint pack_bf2(float a, float b){
  return (uint)f2b(a) | ((uint)f2b(b) << 16);
}
__device__ __forceinline__ float lo16(uint u){ union{uint a;float f;}x; x.a=u<<16; return x.f; }
__device__ __forceinline__ float hi16(uint u){ union{uint a;float f;}x; x.a=u&0xffff0000u; return x.f; }
__device__ __forceinline__ float gelu_exact(float v){
  return 0.5f * v * (1.0f + erff(v * 0.70710678118654752f));
}

// ---------------------------------------------------------------------------
// 64x64-tile MFMA bf16 GEMM (unchanged)
// ---------------------------------------------------------------------------
template<int AF32, int ACT>
__global__ __launch_bounds__(256) void gemm_kernel(
    const void* __restrict__ Av, const float* __restrict__ W, int ldw,
    const float* __restrict__ bias, const float* residf,
    float* Cf, ushort* Cb,
    int M, int N, int K, float scale)
{
  __shared__ __align__(16) ushort Al[64*40];
  __shared__ __align__(16) ushort Bl[64*40];
  const int nb = N >> 6;
  const int rb = blockIdx.x / nb, cb = blockIdx.x % nb;
  const int tid = threadIdx.x;
  const int w = tid >> 6, l = tid & 63;
  f32x4 acc[4];
#pragma unroll
  for(int i=0;i<4;i++) acc[i] = (f32x4){0.f,0.f,0.f,0.f};
  const int ar = tid >> 2, ai = (tid & 3) << 3;
  const int bk = tid >> 3, bn = (tid & 7) << 3;
  for(int kb = 0; kb < K; kb += 32){
    uint4 au;
    if(AF32){
      const float* Ap = (const float*)Av + (size_t)(rb*64 + ar)*K + kb + ai;
      float4 f0 = *(const float4*)Ap;
      float4 f1 = *(const float4*)(Ap + 4);
      au.x = pack_bf2(f0.x,f0.y); au.y = pack_bf2(f0.z,f0.w);
      au.z = pack_bf2(f1.x,f1.y); au.w = pack_bf2(f1.z,f1.w);
    } else {
      au = *(const uint4*)((const ushort*)Av + (size_t)(rb*64 + ar)*K + kb + ai);
    }
    const float* Wp = W + (size_t)(kb + bk)*ldw + cb*64 + bn;
    float4 w0 = *(const float4*)Wp;
    float4 w1 = *(const float4*)(Wp + 4);
    ushort bs[8];
    bs[0]=f2b(w0.x); bs[1]=f2b(w0.y); bs[2]=f2b(w0.z); bs[3]=f2b(w0.w);
    bs[4]=f2b(w1.x); bs[5]=f2b(w1.y); bs[6]=f2b(w1.z); bs[7]=f2b(w1.w);
    __syncthreads();
    *(uint4*)&Al[ar*40 + ai] = au;
#pragma unroll
    for(int i=0;i<8;i++) Bl[(bn+i)*40 + bk] = bs[i];
    __syncthreads();
    bf16x8 af = *(const bf16x8*)&Al[(w*16 + (l&15))*40 + (l>>4)*8];
#pragma unroll
    for(int c4=0;c4<4;c4++){
      bf16x8 bfv = *(const bf16x8*)&Bl[(c4*16 + (l&15))*40 + (l>>4)*8];
      acc[c4] = __builtin_amdgcn_mfma_f32_16x16x32_bf16(af, bfv, acc[c4], 0,0,0);
    }
  }
#pragma unroll
  for(int c4=0;c4<4;c4++){
#pragma unroll
    for(int r=0;r<4;r++){
      int row = rb*64 + w*16 + (l>>4)*4 + r;
      int col = cb*64 + c4*16 + (l&15);
      size_t idx = (size_t)row*N + col;
      float vv = acc[c4][r];
      if(bias) vv += bias[col];
      vv *= scale;
      if(residf) vv += residf[idx];
      if(ACT) vv = gelu_exact(vv);
      if(Cf) Cf[idx] = vv;
      if(Cb) Cb[idx] = f2b(vv);
    }
  }
}

// ---------------------------------------------------------------------------
// Causal self-attention (unchanged)
// ---------------------------------------------------------------------------
__global__ __launch_bounds__(256) void attn_kernel(const ushort* __restrict__ Q,
    const ushort* __restrict__ K, const ushort* __restrict__ V, ushort* __restrict__ O)
{
  __shared__ float s[16*520];
  __shared__ float kt[64*66];
  __shared__ float rowm[16], rowr[16], redx[256];
  const int bid = blockIdx.x;
  const int qb = bid & 31, h = (bid>>5)&3, b = bid>>7;
  const int tid = threadIdx.x;
  const int qi = tid >> 4, jj = tid & 15;
  const int qrow = qb*16 + qi;
  float qreg[64];
  {
    const ushort* qp = Q + ((size_t)(b*512 + qrow))*256 + h*64;
#pragma unroll
    for(int d=0; d<64; d++) qreg[d] = b2f(qp[d])*0.125f;
  }
  const int ntile = (qb*16 + 79) >> 6;
  for(int jt=0; jt<ntile; jt++){
    {
      int jr = tid >> 2, d0 = (tid & 3) << 4;
      const ushort* kp = K + ((size_t)(b*512 + jt*64 + jr))*256 + h*64 + d0;
#pragma unroll
      for(int i=0;i<16;i++) kt[jr*66 + d0 + i] = b2f(kp[i]);
    }
    __syncthreads();
#pragma unroll
    for(int jl=0;jl<4;jl++){
      int jloc = jj*4 + jl;
      int j = jt*64 + jloc;
      float a = 0.f;
#pragma unroll
      for(int d=0; d<64; d++) a += qreg[d]*kt[jloc*66 + d];
      s[qi*520 + j] = (j <= qrow) ? a : -1e30f;
    }
    __syncthreads();
  }
  const int nj = ntile*64;
  float m = -1e30f;
  for(int j=jj; j<nj; j+=16) m = fmaxf(m, s[qi*520 + j]);
  redx[jj*16 + qi] = m;
  __syncthreads();
  if(tid < 16){
    float mm = -1e30f;
#pragma unroll
    for(int k2=0;k2<16;k2++) mm = fmaxf(mm, redx[k2*16 + tid]);
    rowm[tid] = mm;
  }
  __syncthreads();
  float mrow = rowm[qi];
  float ssum = 0.f;
  for(int j=jj; j<nj; j+=16){
    float e = __expf(s[qi*520+j] - mrow);
    s[qi*520+j] = e; ssum += e;
  }
  redx[jj*16 + qi] = ssum;
  __syncthreads();
  if(tid < 16){
    float t2 = 0.f;
#pragma unroll
    for(int k2=0;k2<16;k2++) t2 += redx[k2*16 + tid];
    rowr[tid] = 1.0f/t2;
  }
  const int dd = jj;
  float acc4[4] = {0,0,0,0};
  for(int jt=0; jt<ntile; jt++){
    __syncthreads();
    {
      int jr = tid >> 2, d0 = (tid & 3) << 4;
      const ushort* vp = V + ((size_t)(b*512 + jt*64 + jr))*256 + h*64 + d0;
#pragma unroll
      for(int i=0;i<16;i++) kt[jr*66 + d0 + i] = b2f(vp[i]);
    }
    __syncthreads();
#pragma unroll
    for(int jl=0;jl<64;jl++){
      float p = s[qi*520 + jt*64 + jl];
#pragma unroll
      for(int i=0;i<4;i++) acc4[i] += p*kt[jl*66 + dd*4 + i];
    }
  }
  float rr = rowr[qi];
  ushort* op = O + ((size_t)(b*512 + qrow))*256 + h*64 + dd*4;
#pragma unroll
  for(int i=0;i<4;i++) op[i] = f2b(acc4[i]*rr);
}

// ---------------------------------------------------------------------------
// LayerNorm / small kernels (unchanged)
// ---------------------------------------------------------------------------
__global__ __launch_bounds__(256) void ln_kernel(const float* __restrict__ in,
    const float* __restrict__ g, const float* __restrict__ be,
    float* outf, ushort* outb)
{
  int row = blockIdx.x*4 + (threadIdx.x>>6);
  int lane = threadIdx.x & 63;
  size_t idx = (size_t)row*256 + lane*4;
  float4 v = *(const float4*)(in + idx);
  float s1 = v.x+v.y+v.z+v.w;
  float s2 = v.x*v.x + v.y*v.y + v.z*v.z + v.w*v.w;
#pragma unroll
  for(int off=32; off; off>>=1){ s1 += __shfl_xor(s1,off); s2 += __shfl_xor(s2,off); }
  float mu = s1*(1.f/256.f);
  float var = s2*(1.f/256.f) - mu*mu;
  float r = rsqrtf(var + 1e-5f);
  float vals[4] = {v.x,v.y,v.z,v.w};
  float4 o4; ushort4 ob;
  float* oo = (float*)&o4; ushort* obp = (ushort*)&ob;
#pragma unroll
  for(int i=0;i<4;i++){
    int d = lane*4 + i;
    float y = (vals[i]-mu)*r*g[d] + be[d];
    oo[i] = y; obp[i] = f2b(y);
  }
  if(outf) *(float4*)(outf+idx) = o4;
  if(outb) *(ushort4*)(outb+idx) = ob;
}

__global__ void guid_kernel(const float* __restrict__ h0, const float* __restrict__ spw,
                            const float* __restrict__ spb, float* __restrict__ guid)
{
  int b = blockIdx.x, c = threadIdx.x;
  float s = spb[c];
  for(int r=0;r<256;r++) s += h0[b*256+r]*spw[r*256+c];
  guid[b*256+c] = s;
}

__global__ void ffnin_kernel(const float* __restrict__ x1, const float* __restrict__ guid,
                             ushort* __restrict__ out)
{
  size_t base = ((size_t)blockIdx.x*256 + threadIdx.x)*8;
  int row = (int)(base >> 8); int bb = row >> 9; int c = (int)(base & 255);
  float4 v0 = *(const float4*)(x1 + base);
  float4 v1 = *(const float4*)(x1 + base + 4);
  const float* gp = guid + bb*256 + c;
  const float* xs = (const float*)&v0;
  ushort o[8];
#pragma unroll
  for(int i=0;i<4;i++) o[i] = f2b(xs[i] + 0.3f*gp[i]);
  const float* xs1 = (const float*)&v1;
#pragma unroll
  for(int i=0;i<4;i++) o[4+i] = f2b(xs1[i] + 0.3f*gp[4+i]);
  *(uint4*)(out + base) = *(uint4*)o;
}

__global__ void bo_kernel(const float* __restrict__ ta_bo, const float* __restrict__ tr_w1,
                          float* __restrict__ bo_f)
{
  int c = threadIdx.x;
  float s = 0.f;
  for(int m=0;m<256;m++) s += ta_bo[m]*tr_w1[(size_t)(256+m)*512 + c];
  bo_f[c] = s;
}

// ---------------------------------------------------------------------------
// Persistent scan. 96 blocks x 512 threads.
// role = bid>>4: 0..3 = X (attention head), 4..5 = Y (MLP half-shard).
// q_t and U_t are PRECOMPUTED GEMMs (qtb, Ubf) — off the critical path.
// Fast path (co-located on one XCD): plain stores + wave0 s_waitcnt + volatile
// sc0 flags; remote fallback: agent-scope release/acquire shadow flags.
// Flags: [0..63] fastX(b*4+hd), [64..95] fastY(b*2+i), [128..191] shadowX,
//        [192..223] shadowY, [256..351] xcc table.
// ---------------------------------------------------------------------------
__global__ __launch_bounds__(512, 1) void scan_kernel(
    const ushort* __restrict__ qtb, const ushort* __restrict__ Ubf,
    const float* __restrict__ Wf, const float* __restrict__ bo_f,
    float* cbuf, float* dbuf, int* flags,
    ushort* kcache, ushort* vcache,
    const float* __restrict__ ta_wk, const float* __restrict__ ta_wv,
    const float* __restrict__ ta_bk, const float* __restrict__ ta_bv,
    const float* __restrict__ tr_w2, const float* __restrict__ tr_b2,
    const float* __restrict__ ln3_g, const float* __restrict__ ln3_b,
    const float* __restrict__ ln4_g, const float* __restrict__ ln4_b,
    const float* __restrict__ h0, float* __restrict__ out_h)
{
  __shared__ float red[1024];
  __shared__ float pbuf[512];
  __shared__ float hbuf[256];
  __shared__ float ctxL[256];
  __shared__ float qbufS[64];
  __shared__ float misc[32];
  __shared__ float glbuf[256];
  __shared__ int cp_same[4];

  const int tid = threadIdx.x;
  const int bid = blockIdx.x;
  const int b = bid & 15;
  const int role = bid >> 4;

  // ---- one-time XCD handshake ----
  int myxcc;
  asm volatile("s_getreg_b32 %0, hwreg(HW_REG_XCC_ID)" : "=s"(myxcc));
  if(tid == 0)
    __hip_atomic_store(&flags[256 + bid], myxcc + 1, __ATOMIC_RELEASE, __HIP_MEMORY_SCOPE_AGENT);
  const int npart = (role < 4) ? 2 : 4;
  if(tid < npart){
    int cbid = (role < 4) ? (64 + tid*16 + b) : (tid*16 + b);
    int v;
    while((v = __hip_atomic_load(&flags[256 + cbid], __ATOMIC_ACQUIRE, __HIP_MEMORY_SCOPE_AGENT)) == 0)
      __builtin_amdgcn_s_sleep(8);
    cp_same[tid] = ((v - 1) == myxcc);
  }
  __syncthreads();
  const int cs0 = cp_same[0], cs1 = cp_same[1];
  const int cs2 = (role<4) ? 1 : cp_same[2], cs3 = (role<4) ? 1 : cp_same[3];
  const int anyrem = !(cs0 && cs1 && cs2 && cs3);

  if(role < 4){
    // ================= X: attention head hd =================
    const int hd = role;
    const int bh = b*4 + hd;
    ushort* kc = kcache + (size_t)bh*512*64;   // [j][d]
    ushort* vc = vcache + (size_t)bh*512*64;   // [j][d]
    const int c = tid & 63, r8 = tid >> 6;
    uint wkp[16], wvp[16];
#pragma unroll
    for(int i=0;i<16;i++){
      int r0 = r8*32 + 2*i, r1 = r0 + 1;
      wkp[i] = pack_bf2(ta_wk[r0*256 + hd*64 + c], ta_wk[r1*256 + hd*64 + c]);
      wvp[i] = pack_bf2(ta_wv[r0*256 + hd*64 + c], ta_wv[r1*256 + hd*64 + c]);
    }
    float prbias = 0.f;
    if(tid < 128){
      int kv = tid >> 6, d = tid & 63;
      prbias = kv ? ta_bv[hd*64+d] : ta_bk[hd*64+d];
    }
    float b2r=0, g3r=0, b3r=0;
    if(tid < 256){
      b2r = tr_b2[tid]; g3r = ln3_g[tid]; b3r = ln3_b[tid];
      hbuf[tid] = h0[b*256 + tid];
    }
    __syncthreads();

#pragma clang loop unroll(disable)
    for(int t=0;t<512;t++){
      if(t > 0){
        // prefetch q row (wave 3) — latency hidden behind matvec
        ushort qpre = 0;
        if(tid >= 192 && tid < 256)
          qpre = qtb[((size_t)(b*512 + t))*256 + hd*64 + (tid - 192)];
        // k/v matvec partials from h_{t-1}
        {
          float sk=0.f, sv=0.f;
#pragma unroll
          for(int i=0;i<16;i++){
            float ha = hbuf[r8*32+2*i], hb2 = hbuf[r8*32+2*i+1];
            sk += ha*lo16(wkp[i]) + hb2*hi16(wkp[i]);
            sv += ha*lo16(wvp[i]) + hb2*hi16(wvp[i]);
          }
          red[r8*64 + c] = sk;
          red[512 + r8*64 + c] = sv;
        }
        __syncthreads();                                   // B1
        if(tid < 128){
          int kv = tid >> 6, d = tid & 63;
          float val = prbias;
#pragma unroll
          for(int i=0;i<8;i++) val += red[kv*512 + i*64 + d];
          ushort u = f2b(val);
          if(kv == 0) kc[(size_t)(t-1)*64 + d] = u;
          else        vc[(size_t)(t-1)*64 + d] = u;
        }
        if(tid >= 192 && tid < 256) qbufS[tid-192] = b2f(qpre)*0.125f;
        __syncthreads();                                   // B2 (drains kv stores)
        // scores j<t + per-wave online softmax (1 barrier)
        const int j = tid;
        float sc = -3.0e38f;
        if(j < t){
          const ushort* kr = kc + (size_t)j*64;
          float a = 0.f;
#pragma unroll
          for(int q8=0;q8<8;q8++){
            uint4 kk = *(const uint4*)(kr + q8*8);
            const uint* kw = (const uint*)&kk;
#pragma unroll
            for(int p=0;p<4;p++){
              a += qbufS[q8*8+2*p]   * lo16(kw[p]);
              a += qbufS[q8*8+2*p+1] * hi16(kw[p]);
            }
          }
          sc = a;
        }
        float wm = sc;
#pragma unroll
        for(int off=32; off; off>>=1) wm = fmaxf(wm, __shfl_xor(wm, off));
        float e = (j < t) ? __expf(sc - wm) : 0.f;
        float ws = e;
#pragma unroll
        for(int off=32; off; off>>=1) ws += __shfl_xor(ws, off);
        pbuf[j] = e;
        if((tid&63)==0){ misc[tid>>6] = wm; misc[8 + (tid>>6)] = ws; }
        __syncthreads();                                   // B3
        float gm = misc[0];
#pragma unroll
        for(int i=1;i<8;i++) gm = fmaxf(gm, misc[i]);
        float gsum = 0.f;
#pragma unroll
        for(int i=0;i<8;i++) gsum += misc[8+i]*__expf(misc[i]-gm);
        float rsum = 1.0f / gsum;
        // ctx partial: wave g handles j in [g*64, g*64+64)
        {
          const int d = tid & 63, g = tid >> 6;
          float sfac = __expf(misc[g] - gm);
          const ushort* vr = vc + (size_t)(g*64)*64 + d;
          float part = 0.f;
#pragma unroll
          for(int i=0;i<64;i++) part += pbuf[g*64 + i] * b2f(vr[(size_t)i*64]);
          red[g*64 + d] = part * sfac;
        }
        __syncthreads();                                   // B4
        if(tid < 64){                                      // wave 0 only
          float cv = 0.f;
#pragma unroll
          for(int g2=0;g2<8;g2++) cv += red[g2*64 + tid];
          cbuf[b*256 + hd*64 + tid] = cv*rsum;             // plain store
          asm volatile("s_waitcnt vmcnt(0)" ::: "memory");
          if(tid==0){
            *(volatile int*)&flags[bh] = t;                // fast flag
            if(anyrem)
              __hip_atomic_store(&flags[128 + bh], t, __ATOMIC_RELEASE, __HIP_MEMORY_SCOPE_AGENT);
          }
        }
      } // t>0

      // wait for 2 delta partials from Y
      if(tid < 2){
        int fast = tid ? cs1 : cs0;
        if(fast){
          while(*(volatile int*)&flags[64 + b*2 + tid] < t+1) __builtin_amdgcn_s_sleep(1);
        } else {
          while(__hip_atomic_load(&flags[192 + b*2 + tid], __ATOMIC_RELAXED, __HIP_MEMORY_SCOPE_AGENT) < t+1)
            __builtin_amdgcn_s_sleep(2);
        }
      }
      __syncthreads();                                     // B5
      if(anyrem) __builtin_amdgcn_fence(__ATOMIC_ACQUIRE, "agent");
      // combine: h = LN3(h + 0.5*(delta + tr_b2))
      float v = 0.f;
      if(tid < 256){
        float dsum = b2r + *(volatile float*)&dbuf[(b*2+0)*256 + tid]
                         + *(volatile float*)&dbuf[(b*2+1)*256 + tid];
        v = hbuf[tid] + 0.5f*dsum;
      }
      float s1 = v, s2 = v*v;
#pragma unroll
      for(int off=32; off; off>>=1){ s1 += __shfl_xor(s1,off); s2 += __shfl_xor(s2,off); }
      if((tid&63)==0){ misc[16 + (tid>>6)] = s1; misc[24 + (tid>>6)] = s2; }
      __syncthreads();                                     // B6
      float mu=0.f, qq=0.f;
#pragma unroll
      for(int i=0;i<8;i++){ mu += misc[16+i]; qq += misc[24+i]; }
      mu *= (1.f/256.f); qq = qq*(1.f/256.f) - mu*mu;
      float rstd = rsqrtf(qq + 1e-5f);
      if(tid < 256) hbuf[tid] = (v - mu)*rstd*g3r + b3r;
      __syncthreads();                                     // B7
    } // t loop

    if(hd == 0){
      float v2 = (tid<256) ? hbuf[tid] : 0.f;
      float s1 = v2, s2 = v2*v2;
#pragma unroll
      for(int off=32; off; off>>=1){ s1 += __shfl_xor(s1,off); s2 += __shfl_xor(s2,off); }
      if((tid&63)==0){ misc[16+(tid>>6)] = s1; misc[24+(tid>>6)] = s2; }
      __syncthreads();
      float mu=0.f, qq=0.f;
#pragma unroll
      for(int i=0;i<8;i++){ mu += misc[16+i]; qq += misc[24+i]; }
      mu *= (1.f/256.f); qq = qq*(1.f/256.f) - mu*mu;
      float rstd = rsqrtf(qq + 1e-5f);
      if(tid<256)
        out_h[b*256 + tid] = (v2-mu)*rstd*ln4_g[tid] + ln4_b[tid];
    }
  } else {
    // ================= Y: MLP half-shard ish (256 cols) =================
    const int ish = role - 4;
    const int out = tid >> 1, s = tid & 1;       // Wf: 2 threads per output
    uint wfp[64];
#pragma unroll
    for(int i=0;i<64;i++){
      int r0 = s*128 + 2*i;
      wfp[i] = pack_bf2(Wf[(size_t)r0*512 + ish*256 + out],
                        Wf[(size_t)(r0+1)*512 + ish*256 + out]);
    }
    uint w2p[64];                                 // w2: 2 threads per output
#pragma unroll
    for(int i=0;i<64;i++){
      int c0 = ish*256 + s*128 + 2*i;
      w2p[i] = pack_bf2(tr_w2[(size_t)c0*256 + out],
                        tr_w2[(size_t)(c0+1)*256 + out]);
    }
    const float borr = bo_f[ish*256 + out];
    __syncthreads();

#pragma clang loop unroll(disable)
    for(int t=0;t<512;t++){
      // prefetch U (includes b1) — independent of ctx
      ushort uvs = Ubf[((size_t)(b*512 + t))*512 + ish*256 + out];
      if(t > 0 && tid < 4){
        int fast = (tid==0)?cs0:(tid==1)?cs1:(tid==2)?cs2:cs3;
        if(fast){
          while(*(volatile int*)&flags[b*4 + tid] < t) __builtin_amdgcn_s_sleep(1);
        } else {
          while(__hip_atomic_load(&flags[128 + b*4 + tid], __ATOMIC_RELAXED, __HIP_MEMORY_SCOPE_AGENT) < t)
            __builtin_amdgcn_s_sleep(2);
        }
      }
      __syncthreads();                                     // B1
      if(t > 0){
        if(anyrem) __builtin_amdgcn_fence(__ATOMIC_ACQUIRE, "agent");
        if(tid < 256) ctxL[tid] = *(volatile float*)&cbuf[b*256 + tid];
      }
      __syncthreads();                                     // B2
      float accf = 0.f;
      if(t > 0){
#pragma unroll
        for(int i=0;i<64;i++)
          accf += ctxL[s*128+2*i]*lo16(wfp[i]) + ctxL[s*128+2*i+1]*hi16(wfp[i]);
        accf += __shfl_xor(accf, 1);
      }
      float g1 = b2f(uvs) + ((t>0) ? (borr + accf) : 0.f);
      if(s == 0) glbuf[out] = gelu_exact(g1);
      __syncthreads();                                     // B3
      {
        float dp = 0.f;
#pragma unroll
        for(int i=0;i<64;i++)
          dp += glbuf[s*128+2*i]*lo16(w2p[i]) + glbuf[s*128+2*i+1]*hi16(w2p[i]);
        dp += __shfl_xor(dp, 1);
        if(s == 0) red[out] = dp;
      }
      __syncthreads();                                     // B4
      if(tid < 64){                                        // wave 0 only
#pragma unroll
        for(int k2=0;k2<4;k2++)
          dbuf[(b*2+ish)*256 + tid + 64*k2] = red[tid + 64*k2];
        asm volatile("s_waitcnt vmcnt(0)" ::: "memory");
        if(tid == 0){
          *(volatile int*)&flags[64 + b*2 + ish] = t+1;    // fast flag
          if(anyrem)
            __hip_atomic_store(&flags[192 + b*2 + ish], t+1, __ATOMIC_RELEASE, __HIP_MEMORY_SCOPE_AGENT);
        }
      }
    }
  }
}

// ---------------------------------------------------------------------------
// Workspace layout (bytes). TOTAL = 29 MiB.
// ---------------------------------------------------------------------------
#define OFF_FLAGS ((size_t)0)          //  2 KB
#define OFF_BOF   ((size_t)2048)       //  2 KB  f32[512]
#define OFF_CBUF  ((size_t)4096)       // 16 KB  f32[16*256]
#define OFF_DBUF  ((size_t)20480)      // 32 KB  f32[16*2*256]
#define OFF_GUID  ((size_t)86016)      // 16 KB  f32[4096]
#define OFF_WF    ((size_t)131072)     // 512 KB f32[256*512]
#define OFF_Z1    ((size_t)(1u<<20))   // 4 MB  (kcache at scan)
#define OFF_Z2    ((size_t)(5u<<20))   // 4 MB  (vcache at scan)
#define OFF_Z3    ((size_t)(9u<<20))   // 4 MB  (qtb at scan)
#define OFF_Z4    ((size_t)(13u<<20))  // 4 MB  (abf)
#define OFF_M     ((size_t)(17u<<20))  // 12 MB (Ubf bf16 8MB at scan)

extern "C" void kernel_launch(void* const* d_in, const int* in_sizes, int n_in,
                              void* d_out, int out_size, void* d_ws, size_t ws_size,
                              hipStream_t stream)
{
  const float* x     = (const float*)d_in[0];
  const float* h0    = (const float*)d_in[1];
  const float* sa_wq = (const float*)d_in[2];
  const float* sa_wk = (const float*)d_in[3];
  const float* sa_wv = (const float*)d_in[4];
  const float* sa_wo = (const float*)d_in[5];
  const float* sa_bq = (const float*)d_in[6];
  const float* sa_bk = (const float*)d_in[7];
  const float* sa_bv = (const float*)d_in[8];
  const float* sa_bo = (const float*)d_in[9];
  const float* f_w1  = (const float*)d_in[10];
  const float* f_b1  = (const float*)d_in[11];
  const float* f_w2  = (const float*)d_in[12];
  const float* f_b2  = (const float*)d_in[13];
  const float* ta_wq = (const float*)d_in[14];
  const float* ta_wk = (const float*)d_in[15];
  const float* ta_wv = (const float*)d_in[16];
  const float* ta_wo = (const float*)d_in[17];
  const float* ta_bq = (const float*)d_in[18];
  const float* ta_bk = (const float*)d_in[19];
  const float* ta_bv = (const float*)d_in[20];
  const float* ta_bo = (const float*)d_in[21];
  const float* tr_w1 = (const float*)d_in[22];
  const float* tr_b1 = (const float*)d_in[23];
  const float* tr_w2 = (const float*)d_in[24];
  const float* tr_b2 = (const float*)d_in[25];
  const float* ps_w  = (const float*)d_in[26];
  const float* ps_b  = (const float*)d_in[27];
  const float* sp_w  = (const float*)d_in[28];
  const float* sp_b  = (const float*)d_in[29];
  const float* ln1_g = (const float*)d_in[30];
  const float* ln1_b = (const float*)d_in[31];
  const float* ln2_g = (const float*)d_in[32];
  const float* ln2_b = (const float*)d_in[33];
  const float* ln3_g = (const float*)d_in[34];
  const float* ln3_b = (const float*)d_in[35];
  const float* ln4_g = (const float*)d_in[36];
  const float* ln4_b = (const float*)d_in[37];

  char* ws = (char*)d_ws;
  int*    flags = (int*)   (ws + OFF_FLAGS);
  float*  bo_f  = (float*) (ws + OFF_BOF);
  float*  cbuf  = (float*) (ws + OFF_CBUF);
  float*  dbuf  = (float*) (ws + OFF_DBUF);
  float*  guid  = (float*) (ws + OFF_GUID);
  float*  Wff   = (float*) (ws + OFF_WF);
  ushort* qb    = (ushort*)(ws + OFF_Z1);
  ushort* kb    = (ushort*)(ws + OFF_Z2);
  ushort* vb    = (ushort*)(ws + OFF_Z3);
  ushort* attnb = (ushort*)(ws + OFF_Z4);
  float*  x0pre = (float*) (ws + OFF_Z1);   // Z1+Z2
  float*  x1f   = (float*) (ws + OFF_Z3);   // Z3+Z4
  ushort* ffnb  = (ushort*)(ws + OFF_M);
  ushort* mid   = (ushort*)(ws + OFF_M + (4u<<20));
  float*  x2pre = (float*) (ws + OFF_Z1);   // Z1+Z2
  ushort* abf   = (ushort*)(ws + OFF_Z4);
  ushort* qtb   = (ushort*)(ws + OFF_Z3);
  ushort* Ubf   = (ushort*)(ws + OFF_M);    // 8 MB bf16 [8192,512]
  ushort* kc    = (ushort*)(ws + OFF_Z1);
  ushort* vc    = (ushort*)(ws + OFF_Z2);
  float*  outb  = (float*)d_out;
  float*  out_h = outb + (out_size - 4096);

  hipMemsetAsync(flags, 0, 2048, stream);

  // ===== parallel prefix =====
  gemm_kernel<1,0><<<512, 256, 0, stream>>>(x, sa_wq, 256, sa_bq, nullptr, nullptr, qb, 8192,256,256, 1.0f);
  gemm_kernel<1,0><<<512, 256, 0, stream>>>(x, sa_wk, 256, sa_bk, nullptr, nullptr, kb, 8192,256,256, 1.0f);
  gemm_kernel<1,0><<<512, 256, 0, stream>>>(x, sa_wv, 256, sa_bv, nullptr, nullptr, vb, 8192,256,256, 1.0f);
  attn_kernel<<<2048, 256, 0, stream>>>(qb, kb, vb, attnb);
  gemm_kernel<0,0><<<512, 256, 0, stream>>>(attnb, sa_wo, 256, sa_bo, x, x0pre, nullptr, 8192,256,256, 1.0f);
  ln_kernel<<<2048, 256, 0, stream>>>(x0pre, ln1_g, ln1_b, x1f, nullptr);
  guid_kernel<<<16, 256, 0, stream>>>(h0, sp_w, sp_b, guid);
  ffnin_kernel<<<1024, 256, 0, stream>>>(x1f, guid, ffnb);
  gemm_kernel<0,1><<<1024, 256, 0, stream>>>(ffnb, f_w1, 1024, f_b1, nullptr, nullptr, mid, 8192,512,256, 1.0f);
  gemm_kernel<0,0><<<512, 256, 0, stream>>>(mid, f_w2, 256, f_b2, x1f, x2pre, nullptr, 8192,256,512, 1.0f);
  gemm_kernel<0,1><<<1024, 256, 0, stream>>>(ffnb, f_w1 + 512, 1024, f_b1 + 512, nullptr, nullptr, mid, 8192,512,256, 1.0f);
  gemm_kernel<0,0><<<512, 256, 0, stream>>>(mid, f_w2 + (size_t)512*256, 256, nullptr, x2pre, x2pre, nullptr, 8192,256,512, 1.0f);
  ln_kernel<<<2048, 256, 0, stream>>>(x2pre, ln2_g, ln2_b, outb, nullptr);   // output 0 (f32)

  // ===== scan precompute (all GEMMs) =====
  gemm_kernel<1,0><<<512, 256, 0, stream>>>(outb, ps_w, 256, ps_b, outb, nullptr, abf, 8192,256,256, 0.3f);
  gemm_kernel<0,0><<<1024, 256, 0, stream>>>(abf, tr_w1, 512, tr_b1, nullptr, nullptr, Ubf, 8192,512,256, 1.0f);
  gemm_kernel<1,0><<<512, 256, 0, stream>>>(outb, ta_wq, 256, ta_bq, nullptr, nullptr, qtb, 8192,256,256, 1.0f);
  gemm_kernel<1,0><<<32, 256, 0, stream>>>(ta_wo, tr_w1 + (size_t)256*512, 512, nullptr, nullptr, Wff, nullptr, 256,512,256, 1.0f);
  bo_kernel<<<1, 512, 0, stream>>>(ta_bo, tr_w1, bo_f);

  // Zero k/v caches (Z1+Z2): unguarded phase-C reads of rows >= t need 0.0.
  hipMemsetAsync(ws + OFF_Z1, 0, (size_t)(8u<<20), stream);

  // ===== sequential scan (persistent pipelined kernel) =====
  scan_kernel<<<96, 512, 0, stream>>>(qtb, Ubf, Wff, bo_f, cbuf, dbuf, flags, kc, vc,
                                      ta_wk, ta_wv, ta_bk, ta_bv, tr_w2, tr_b2,
                                      ln3_g, ln3_b, ln4_g, ln4_b, h0, out_h);
}

// Round 8
// 5847.493 us; speedup vs baseline: 1.0617x; 1.0617x over previous
//
#include <hip/hip_runtime.h>
#include <hip/hip_bf16.h>

typedef __bf16 bf16x8 __attribute__((ext_vector_type(8)));
typedef float f32x4 __attribute__((ext_vector_type(4)));

__device__ __forceinline__ float b2f(ushort u){
  union { uint u; float f; } x; x.u = ((uint)u) << 16; return x.f;
}
__device__ __forceinline__ ushort f2b(float f){
  union { float f; uint u; } x; x.f = f;
  uint r = x.u + 0x7fff + ((x.u >> 16) & 1);
  return (ushort)(r >> 16);
}
__device__ __forceinline__ uint pack_bf2(float a, float b){
  return (uint)f2b(a) | ((uint)f2b(b) << 16);
}
__device__ __forceinline__ float lo16(uint u){ union{uint a;float f;}x; x.a=u<<16; return x.f; }
__device__ __forceinline__ float hi16(uint u){ union{uint a;float f;}x; x.a=u&0xffff0000u; return x.f; }
__device__ __forceinline__ float gelu_exact(float v){
  return 0.5f * v * (1.0f + erff(v * 0.70710678118654752f));
}

// ---------------------------------------------------------------------------
// 64x64-tile MFMA bf16 GEMM (unchanged)
// ---------------------------------------------------------------------------
template<int AF32, int ACT>
__global__ __launch_bounds__(256) void gemm_kernel(
    const void* __restrict__ Av, const float* __restrict__ W, int ldw,
    const float* __restrict__ bias, const float* residf,
    float* Cf, ushort* Cb,
    int M, int N, int K, float scale)
{
  __shared__ __align__(16) ushort Al[64*40];
  __shared__ __align__(16) ushort Bl[64*40];
  const int nb = N >> 6;
  const int rb = blockIdx.x / nb, cb = blockIdx.x % nb;
  const int tid = threadIdx.x;
  const int w = tid >> 6, l = tid & 63;
  f32x4 acc[4];
#pragma unroll
  for(int i=0;i<4;i++) acc[i] = (f32x4){0.f,0.f,0.f,0.f};
  const int ar = tid >> 2, ai = (tid & 3) << 3;
  const int bk = tid >> 3, bn = (tid & 7) << 3;
  for(int kb = 0; kb < K; kb += 32){
    uint4 au;
    if(AF32){
      const float* Ap = (const float*)Av + (size_t)(rb*64 + ar)*K + kb + ai;
      float4 f0 = *(const float4*)Ap;
      float4 f1 = *(const float4*)(Ap + 4);
      au.x = pack_bf2(f0.x,f0.y); au.y = pack_bf2(f0.z,f0.w);
      au.z = pack_bf2(f1.x,f1.y); au.w = pack_bf2(f1.z,f1.w);
    } else {
      au = *(const uint4*)((const ushort*)Av + (size_t)(rb*64 + ar)*K + kb + ai);
    }
    const float* Wp = W + (size_t)(kb + bk)*ldw + cb*64 + bn;
    float4 w0 = *(const float4*)Wp;
    float4 w1 = *(const float4*)(Wp + 4);
    ushort bs[8];
    bs[0]=f2b(w0.x); bs[1]=f2b(w0.y); bs[2]=f2b(w0.z); bs[3]=f2b(w0.w);
    bs[4]=f2b(w1.x); bs[5]=f2b(w1.y); bs[6]=f2b(w1.z); bs[7]=f2b(w1.w);
    __syncthreads();
    *(uint4*)&Al[ar*40 + ai] = au;
#pragma unroll
    for(int i=0;i<8;i++) Bl[(bn+i)*40 + bk] = bs[i];
    __syncthreads();
    bf16x8 af = *(const bf16x8*)&Al[(w*16 + (l&15))*40 + (l>>4)*8];
#pragma unroll
    for(int c4=0;c4<4;c4++){
      bf16x8 bfv = *(const bf16x8*)&Bl[(c4*16 + (l&15))*40 + (l>>4)*8];
      acc[c4] = __builtin_amdgcn_mfma_f32_16x16x32_bf16(af, bfv, acc[c4], 0,0,0);
    }
  }
#pragma unroll
  for(int c4=0;c4<4;c4++){
#pragma unroll
    for(int r=0;r<4;r++){
      int row = rb*64 + w*16 + (l>>4)*4 + r;
      int col = cb*64 + c4*16 + (l&15);
      size_t idx = (size_t)row*N + col;
      float vv = acc[c4][r];
      if(bias) vv += bias[col];
      vv *= scale;
      if(residf) vv += residf[idx];
      if(ACT) vv = gelu_exact(vv);
      if(Cf) Cf[idx] = vv;
      if(Cb) Cb[idx] = f2b(vv);
    }
  }
}

// ---------------------------------------------------------------------------
// Causal self-attention (unchanged)
// ---------------------------------------------------------------------------
__global__ __launch_bounds__(256) void attn_kernel(const ushort* __restrict__ Q,
    const ushort* __restrict__ K, const ushort* __restrict__ V, ushort* __restrict__ O)
{
  __shared__ float s[16*520];
  __shared__ float kt[64*66];
  __shared__ float rowm[16], rowr[16], redx[256];
  const int bid = blockIdx.x;
  const int qb = bid & 31, h = (bid>>5)&3, b = bid>>7;
  const int tid = threadIdx.x;
  const int qi = tid >> 4, jj = tid & 15;
  const int qrow = qb*16 + qi;
  float qreg[64];
  {
    const ushort* qp = Q + ((size_t)(b*512 + qrow))*256 + h*64;
#pragma unroll
    for(int d=0; d<64; d++) qreg[d] = b2f(qp[d])*0.125f;
  }
  const int ntile = (qb*16 + 79) >> 6;
  for(int jt=0; jt<ntile; jt++){
    {
      int jr = tid >> 2, d0 = (tid & 3) << 4;
      const ushort* kp = K + ((size_t)(b*512 + jt*64 + jr))*256 + h*64 + d0;
#pragma unroll
      for(int i=0;i<16;i++) kt[jr*66 + d0 + i] = b2f(kp[i]);
    }
    __syncthreads();
#pragma unroll
    for(int jl=0;jl<4;jl++){
      int jloc = jj*4 + jl;
      int j = jt*64 + jloc;
      float a = 0.f;
#pragma unroll
      for(int d=0; d<64; d++) a += qreg[d]*kt[jloc*66 + d];
      s[qi*520 + j] = (j <= qrow) ? a : -1e30f;
    }
    __syncthreads();
  }
  const int nj = ntile*64;
  float m = -1e30f;
  for(int j=jj; j<nj; j+=16) m = fmaxf(m, s[qi*520 + j]);
  redx[jj*16 + qi] = m;
  __syncthreads();
  if(tid < 16){
    float mm = -1e30f;
#pragma unroll
    for(int k2=0;k2<16;k2++) mm = fmaxf(mm, redx[k2*16 + tid]);
    rowm[tid] = mm;
  }
  __syncthreads();
  float mrow = rowm[qi];
  float ssum = 0.f;
  for(int j=jj; j<nj; j+=16){
    float e = __expf(s[qi*520+j] - mrow);
    s[qi*520+j] = e; ssum += e;
  }
  redx[jj*16 + qi] = ssum;
  __syncthreads();
  if(tid < 16){
    float t2 = 0.f;
#pragma unroll
    for(int k2=0;k2<16;k2++) t2 += redx[k2*16 + tid];
    rowr[tid] = 1.0f/t2;
  }
  const int dd = jj;
  float acc4[4] = {0,0,0,0};
  for(int jt=0; jt<ntile; jt++){
    __syncthreads();
    {
      int jr = tid >> 2, d0 = (tid & 3) << 4;
      const ushort* vp = V + ((size_t)(b*512 + jt*64 + jr))*256 + h*64 + d0;
#pragma unroll
      for(int i=0;i<16;i++) kt[jr*66 + d0 + i] = b2f(vp[i]);
    }
    __syncthreads();
#pragma unroll
    for(int jl=0;jl<64;jl++){
      float p = s[qi*520 + jt*64 + jl];
#pragma unroll
      for(int i=0;i<4;i++) acc4[i] += p*kt[jl*66 + dd*4 + i];
    }
  }
  float rr = rowr[qi];
  ushort* op = O + ((size_t)(b*512 + qrow))*256 + h*64 + dd*4;
#pragma unroll
  for(int i=0;i<4;i++) op[i] = f2b(acc4[i]*rr);
}

// ---------------------------------------------------------------------------
// LayerNorm / small kernels (unchanged)
// ---------------------------------------------------------------------------
__global__ __launch_bounds__(256) void ln_kernel(const float* __restrict__ in,
    const float* __restrict__ g, const float* __restrict__ be,
    float* outf, ushort* outb)
{
  int row = blockIdx.x*4 + (threadIdx.x>>6);
  int lane = threadIdx.x & 63;
  size_t idx = (size_t)row*256 + lane*4;
  float4 v = *(const float4*)(in + idx);
  float s1 = v.x+v.y+v.z+v.w;
  float s2 = v.x*v.x + v.y*v.y + v.z*v.z + v.w*v.w;
#pragma unroll
  for(int off=32; off; off>>=1){ s1 += __shfl_xor(s1,off); s2 += __shfl_xor(s2,off); }
  float mu = s1*(1.f/256.f);
  float var = s2*(1.f/256.f) - mu*mu;
  float r = rsqrtf(var + 1e-5f);
  float vals[4] = {v.x,v.y,v.z,v.w};
  float4 o4; ushort4 ob;
  float* oo = (float*)&o4; ushort* obp = (ushort*)&ob;
#pragma unroll
  for(int i=0;i<4;i++){
    int d = lane*4 + i;
    float y = (vals[i]-mu)*r*g[d] + be[d];
    oo[i] = y; obp[i] = f2b(y);
  }
  if(outf) *(float4*)(outf+idx) = o4;
  if(outb) *(ushort4*)(outb+idx) = ob;
}

__global__ void guid_kernel(const float* __restrict__ h0, const float* __restrict__ spw,
                            const float* __restrict__ spb, float* __restrict__ guid)
{
  int b = blockIdx.x, c = threadIdx.x;
  float s = spb[c];
  for(int r=0;r<256;r++) s += h0[b*256+r]*spw[r*256+c];
  guid[b*256+c] = s;
}

__global__ void ffnin_kernel(const float* __restrict__ x1, const float* __restrict__ guid,
                             ushort* __restrict__ out)
{
  size_t base = ((size_t)blockIdx.x*256 + threadIdx.x)*8;
  int row = (int)(base >> 8); int bb = row >> 9; int c = (int)(base & 255);
  float4 v0 = *(const float4*)(x1 + base);
  float4 v1 = *(const float4*)(x1 + base + 4);
  const float* gp = guid + bb*256 + c;
  const float* xs = (const float*)&v0;
  ushort o[8];
#pragma unroll
  for(int i=0;i<4;i++) o[i] = f2b(xs[i] + 0.3f*gp[i]);
  const float* xs1 = (const float*)&v1;
#pragma unroll
  for(int i=0;i<4;i++) o[4+i] = f2b(xs1[i] + 0.3f*gp[4+i]);
  *(uint4*)(out + base) = *(uint4*)o;
}

__global__ void bo_kernel(const float* __restrict__ ta_bo, const float* __restrict__ tr_w1,
                          float* __restrict__ bo_f)
{
  int c = threadIdx.x;
  float s = 0.f;
  for(int m=0;m<256;m++) s += ta_bo[m]*tr_w1[(size_t)(256+m)*512 + c];
  bo_f[c] = s;
}

// ---------------------------------------------------------------------------
// Persistent scan. 96 blocks x 512 threads. Dynamic LDS: k/v caches (135 KB).
// role = bid>>4: 0..3 = X (attention head), 4..5 = Y (MLP half-shard).
// kc[j][66] u16 rows (stride 33 dw -> 2-way bank alias = free);
// vc[j][66] u16 rows; both zero-initialized in-kernel.
// Cross-WG: fast path sc0 flags (co-located XCD), agent-scope fallback.
// ---------------------------------------------------------------------------
__global__ __launch_bounds__(512, 1) void scan_kernel(
    const ushort* __restrict__ qtb, const ushort* __restrict__ Ubf,
    const float* __restrict__ Wf, const float* __restrict__ bo_f,
    float* cbuf, float* dbuf, int* flags,
    const float* __restrict__ ta_wk, const float* __restrict__ ta_wv,
    const float* __restrict__ ta_bk, const float* __restrict__ ta_bv,
    const float* __restrict__ tr_w2, const float* __restrict__ tr_b2,
    const float* __restrict__ ln3_g, const float* __restrict__ ln3_b,
    const float* __restrict__ ln4_g, const float* __restrict__ ln4_b,
    const float* __restrict__ h0, float* __restrict__ out_h)
{
  __shared__ float red[1024];
  __shared__ float pbuf[512];
  __shared__ float hbuf[256];
  __shared__ float ctxL[264];     // padded halves: s*130 + [0..127]
  __shared__ float qbufS[64];
  __shared__ float misc[32];
  __shared__ float glbuf[264];    // padded halves
  __shared__ int cp_same[4];
  extern __shared__ __align__(16) ushort dynL[];
  ushort* kcL = dynL;             // [512][66]
  ushort* vcL = dynL + 512*66;    // [512][66]

  const int tid = threadIdx.x;
  const int bid = blockIdx.x;
  const int b = bid & 15;
  const int role = bid >> 4;

  // zero k/v caches (phase C tail reads need 0.0, LDS is uninitialized)
  for(int i = tid; i < 512*66; i += 512){ kcL[i] = 0; vcL[i] = 0; }

  // ---- one-time XCD handshake ----
  int myxcc;
  asm volatile("s_getreg_b32 %0, hwreg(HW_REG_XCC_ID)" : "=s"(myxcc));
  if(tid == 0)
    __hip_atomic_store(&flags[256 + bid], myxcc + 1, __ATOMIC_RELEASE, __HIP_MEMORY_SCOPE_AGENT);
  const int npart = (role < 4) ? 2 : 4;
  if(tid < npart){
    int cbid = (role < 4) ? (64 + tid*16 + b) : (tid*16 + b);
    int v;
    while((v = __hip_atomic_load(&flags[256 + cbid], __ATOMIC_ACQUIRE, __HIP_MEMORY_SCOPE_AGENT)) == 0)
      __builtin_amdgcn_s_sleep(8);
    cp_same[tid] = ((v - 1) == myxcc);
  }
  __syncthreads();
  const int cs0 = cp_same[0], cs1 = cp_same[1];
  const int cs2 = (role<4) ? 1 : cp_same[2], cs3 = (role<4) ? 1 : cp_same[3];
  const int anyrem = !(cs0 && cs1 && cs2 && cs3);

  if(role < 4){
    // ================= X: attention head hd =================
    const int hd = role;
    const int bh = b*4 + hd;
    const int c = tid & 63, r8 = tid >> 6;
    uint wkp[16], wvp[16];
#pragma unroll
    for(int i=0;i<16;i++){
      int r0 = r8*32 + 2*i, r1 = r0 + 1;
      wkp[i] = pack_bf2(ta_wk[r0*256 + hd*64 + c], ta_wk[r1*256 + hd*64 + c]);
      wvp[i] = pack_bf2(ta_wv[r0*256 + hd*64 + c], ta_wv[r1*256 + hd*64 + c]);
    }
    float prbias = 0.f;
    if(tid < 128){
      int kv = tid >> 6, d = tid & 63;
      prbias = kv ? ta_bv[hd*64+d] : ta_bk[hd*64+d];
    }
    float b2r=0, g3r=0, b3r=0;
    if(tid < 256){
      b2r = tr_b2[tid]; g3r = ln3_g[tid]; b3r = ln3_b[tid];
      hbuf[tid] = h0[b*256 + tid];
    }
    __syncthreads();

#pragma clang loop unroll(disable)
    for(int t=0;t<512;t++){
      if(t > 0){
        // prefetch q row (wave 3)
        ushort qpre = 0;
        if(tid >= 192 && tid < 256)
          qpre = qtb[((size_t)(b*512 + t))*256 + hd*64 + (tid - 192)];
        // k/v matvec partials from h_{t-1} (hbuf reads are wave-uniform -> broadcast)
        {
          float sk=0.f, sv=0.f;
#pragma unroll
          for(int i=0;i<16;i++){
            float ha = hbuf[r8*32+2*i], hb2 = hbuf[r8*32+2*i+1];
            sk += ha*lo16(wkp[i]) + hb2*hi16(wkp[i]);
            sv += ha*lo16(wvp[i]) + hb2*hi16(wvp[i]);
          }
          red[r8*64 + c] = sk;
          red[512 + r8*64 + c] = sv;
        }
        __syncthreads();                                   // B1
        if(tid < 128){
          int kv = tid >> 6, d = tid & 63;
          float val = prbias;
#pragma unroll
          for(int i=0;i<8;i++) val += red[kv*512 + i*64 + d];
          ushort u = f2b(val);
          if(kv == 0) kcL[(t-1)*66 + d] = u;
          else        vcL[(t-1)*66 + d] = u;
        }
        if(tid >= 192 && tid < 256) qbufS[tid-192] = b2f(qpre)*0.125f;
        __syncthreads();                                   // B2
        // scores j<t from LDS kc (32 x b32, 2-way alias = free)
        const int j = tid;
        float sc = -3.0e38f;
        if(j < t){
          const uint* kr = (const uint*)(kcL + j*66);
          float a = 0.f;
#pragma unroll
          for(int w=0; w<32; w++){
            uint kk = kr[w];
            a += qbufS[2*w]   * lo16(kk);
            a += qbufS[2*w+1] * hi16(kk);
          }
          sc = a;
        }
        float wm = sc;
#pragma unroll
        for(int off=32; off; off>>=1) wm = fmaxf(wm, __shfl_xor(wm, off));
        float e = (j < t) ? __expf(sc - wm) : 0.f;
        float ws = e;
#pragma unroll
        for(int off=32; off; off>>=1) ws += __shfl_xor(ws, off);
        pbuf[j] = e;
        if((tid&63)==0){ misc[tid>>6] = wm; misc[8 + (tid>>6)] = ws; }
        __syncthreads();                                   // B3
        float gm = misc[0];
#pragma unroll
        for(int i=1;i<8;i++) gm = fmaxf(gm, misc[i]);
        float gsum = 0.f;
#pragma unroll
        for(int i=0;i<8;i++) gsum += misc[8+i]*__expf(misc[i]-gm);
        float rsum = 1.0f / gsum;
        // ctx partial from LDS vc: wave g handles j in [g*64, g*64+64)
        {
          const int d = tid & 63, g = tid >> 6;
          float sfac = __expf(misc[g] - gm);
          float part = 0.f;
#pragma unroll
          for(int i=0;i<64;i++){
            int j2 = g*64 + i;
            part += pbuf[j2] * b2f(vcL[j2*66 + d]);
          }
          red[g*64 + d] = part * sfac;
        }
        __syncthreads();                                   // B4
        if(tid < 64){                                      // wave 0 only
          float cv = 0.f;
#pragma unroll
          for(int g2=0;g2<8;g2++) cv += red[g2*64 + tid];
          cbuf[b*256 + hd*64 + tid] = cv*rsum;
          asm volatile("s_waitcnt vmcnt(0)" ::: "memory");
          if(tid==0){
            *(volatile int*)&flags[bh] = t;
            if(anyrem)
              __hip_atomic_store(&flags[128 + bh], t, __ATOMIC_RELEASE, __HIP_MEMORY_SCOPE_AGENT);
          }
        }
      } // t>0

      // wait for 2 delta partials from Y
      if(tid < 2){
        int fast = tid ? cs1 : cs0;
        if(fast){
          while(*(volatile int*)&flags[64 + b*2 + tid] < t+1) __builtin_amdgcn_s_sleep(1);
        } else {
          while(__hip_atomic_load(&flags[192 + b*2 + tid], __ATOMIC_RELAXED, __HIP_MEMORY_SCOPE_AGENT) < t+1)
            __builtin_amdgcn_s_sleep(2);
        }
      }
      __syncthreads();                                     // B5
      if(anyrem) __builtin_amdgcn_fence(__ATOMIC_ACQUIRE, "agent");
      float v = 0.f;
      if(tid < 256){
        float dsum = b2r + *(volatile float*)&dbuf[(b*2+0)*256 + tid]
                         + *(volatile float*)&dbuf[(b*2+1)*256 + tid];
        v = hbuf[tid] + 0.5f*dsum;
      }
      float s1 = v, s2 = v*v;
#pragma unroll
      for(int off=32; off; off>>=1){ s1 += __shfl_xor(s1,off); s2 += __shfl_xor(s2,off); }
      if((tid&63)==0){ misc[16 + (tid>>6)] = s1; misc[24 + (tid>>6)] = s2; }
      __syncthreads();                                     // B6
      float mu=0.f, qq=0.f;
#pragma unroll
      for(int i=0;i<8;i++){ mu += misc[16+i]; qq += misc[24+i]; }
      mu *= (1.f/256.f); qq = qq*(1.f/256.f) - mu*mu;
      float rstd = rsqrtf(qq + 1e-5f);
      if(tid < 256) hbuf[tid] = (v - mu)*rstd*g3r + b3r;
      __syncthreads();                                     // B7
    } // t loop

    if(hd == 0){
      float v2 = (tid<256) ? hbuf[tid] : 0.f;
      float s1 = v2, s2 = v2*v2;
#pragma unroll
      for(int off=32; off; off>>=1){ s1 += __shfl_xor(s1,off); s2 += __shfl_xor(s2,off); }
      if((tid&63)==0){ misc[16+(tid>>6)] = s1; misc[24+(tid>>6)] = s2; }
      __syncthreads();
      float mu=0.f, qq=0.f;
#pragma unroll
      for(int i=0;i<8;i++){ mu += misc[16+i]; qq += misc[24+i]; }
      mu *= (1.f/256.f); qq = qq*(1.f/256.f) - mu*mu;
      float rstd = rsqrtf(qq + 1e-5f);
      if(tid<256)
        out_h[b*256 + tid] = (v2-mu)*rstd*ln4_g[tid] + ln4_b[tid];
    }
  } else {
    // ================= Y: MLP half-shard ish (256 cols) =================
    const int ish = role - 4;
    const int out = tid >> 1, s = tid & 1;
    uint wfp[64];
#pragma unroll
    for(int i=0;i<64;i++){
      int r0 = s*128 + 2*i;
      wfp[i] = pack_bf2(Wf[(size_t)r0*512 + ish*256 + out],
                        Wf[(size_t)(r0+1)*512 + ish*256 + out]);
    }
    uint w2p[64];
#pragma unroll
    for(int i=0;i<64;i++){
      int c0 = ish*256 + s*128 + 2*i;
      w2p[i] = pack_bf2(tr_w2[(size_t)c0*256 + out],
                        tr_w2[(size_t)(c0+1)*256 + out]);
    }
    const float borr = bo_f[ish*256 + out];
    __syncthreads();

#pragma clang loop unroll(disable)
    for(int t=0;t<512;t++){
      ushort uvs = Ubf[((size_t)(b*512 + t))*512 + ish*256 + out];
      if(t > 0 && tid < 4){
        int fast = (tid==0)?cs0:(tid==1)?cs1:(tid==2)?cs2:cs3;
        if(fast){
          while(*(volatile int*)&flags[b*4 + tid] < t) __builtin_amdgcn_s_sleep(1);
        } else {
          while(__hip_atomic_load(&flags[128 + b*4 + tid], __ATOMIC_RELAXED, __HIP_MEMORY_SCOPE_AGENT) < t)
            __builtin_amdgcn_s_sleep(2);
        }
      }
      __syncthreads();                                     // B1
      if(t > 0){
        if(anyrem) __builtin_amdgcn_fence(__ATOMIC_ACQUIRE, "agent");
        if(tid < 256)
          ctxL[(tid>>7)*130 + (tid&127)] = *(volatile float*)&cbuf[b*256 + tid];
      }
      __syncthreads();                                     // B2
      float accf = 0.f;
      if(t > 0){
        const float* cp = &ctxL[s*130];
#pragma unroll
        for(int i=0;i<64;i++)
          accf += cp[2*i]*lo16(wfp[i]) + cp[2*i+1]*hi16(wfp[i]);
        accf += __shfl_xor(accf, 1);
      }
      float g1 = b2f(uvs) + ((t>0) ? (borr + accf) : 0.f);
      if(s == 0) glbuf[(out>>7)*130 + (out&127)] = gelu_exact(g1);
      __syncthreads();                                     // B3
      {
        const float* gp = &glbuf[s*130];
        float dp = 0.f;
#pragma unroll
        for(int i=0;i<64;i++)
          dp += gp[2*i]*lo16(w2p[i]) + gp[2*i+1]*hi16(w2p[i]);
        dp += __shfl_xor(dp, 1);
        if(s == 0) red[out] = dp;
      }
      __syncthreads();                                     // B4
      if(tid < 64){                                        // wave 0 only
#pragma unroll
        for(int k2=0;k2<4;k2++)
          dbuf[(b*2+ish)*256 + tid + 64*k2] = red[tid + 64*k2];
        asm volatile("s_waitcnt vmcnt(0)" ::: "memory");
        if(tid == 0){
          *(volatile int*)&flags[64 + b*2 + ish] = t+1;
          if(anyrem)
            __hip_atomic_store(&flags[192 + b*2 + ish], t+1, __ATOMIC_RELEASE, __HIP_MEMORY_SCOPE_AGENT);
        }
      }
    }
  }
}

// ---------------------------------------------------------------------------
// Workspace layout (bytes). TOTAL = 29 MiB.
// ---------------------------------------------------------------------------
#define OFF_FLAGS ((size_t)0)
#define OFF_BOF   ((size_t)2048)
#define OFF_CBUF  ((size_t)4096)
#define OFF_DBUF  ((size_t)20480)
#define OFF_GUID  ((size_t)86016)
#define OFF_WF    ((size_t)131072)
#define OFF_Z1    ((size_t)(1u<<20))
#define OFF_Z2    ((size_t)(5u<<20))
#define OFF_Z3    ((size_t)(9u<<20))
#define OFF_Z4    ((size_t)(13u<<20))
#define OFF_M     ((size_t)(17u<<20))

#define SCAN_DYN_LDS (512*66*2*2)   // 135168 B

extern "C" void kernel_launch(void* const* d_in, const int* in_sizes, int n_in,
                              void* d_out, int out_size, void* d_ws, size_t ws_size,
                              hipStream_t stream)
{
  const float* x     = (const float*)d_in[0];
  const float* h0    = (const float*)d_in[1];
  const float* sa_wq = (const float*)d_in[2];
  const float* sa_wk = (const float*)d_in[3];
  const float* sa_wv = (const float*)d_in[4];
  const float* sa_wo = (const float*)d_in[5];
  const float* sa_bq = (const float*)d_in[6];
  const float* sa_bk = (const float*)d_in[7];
  const float* sa_bv = (const float*)d_in[8];
  const float* sa_bo = (const float*)d_in[9];
  const float* f_w1  = (const float*)d_in[10];
  const float* f_b1  = (const float*)d_in[11];
  const float* f_w2  = (const float*)d_in[12];
  const float* f_b2  = (const float*)d_in[13];
  const float* ta_wq = (const float*)d_in[14];
  const float* ta_wk = (const float*)d_in[15];
  const float* ta_wv = (const float*)d_in[16];
  const float* ta_wo = (const float*)d_in[17];
  const float* ta_bq = (const float*)d_in[18];
  const float* ta_bk = (const float*)d_in[19];
  const float* ta_bv = (const float*)d_in[20];
  const float* ta_bo = (const float*)d_in[21];
  const float* tr_w1 = (const float*)d_in[22];
  const float* tr_b1 = (const float*)d_in[23];
  const float* tr_w2 = (const float*)d_in[24];
  const float* tr_b2 = (const float*)d_in[25];
  const float* ps_w  = (const float*)d_in[26];
  const float* ps_b  = (const float*)d_in[27];
  const float* sp_w  = (const float*)d_in[28];
  const float* sp_b  = (const float*)d_in[29];
  const float* ln1_g = (const float*)d_in[30];
  const float* ln1_b = (const float*)d_in[31];
  const float* ln2_g = (const float*)d_in[32];
  const float* ln2_b = (const float*)d_in[33];
  const float* ln3_g = (const float*)d_in[34];
  const float* ln3_b = (const float*)d_in[35];
  const float* ln4_g = (const float*)d_in[36];
  const float* ln4_b = (const float*)d_in[37];

  char* ws = (char*)d_ws;
  int*    flags = (int*)   (ws + OFF_FLAGS);
  float*  bo_f  = (float*) (ws + OFF_BOF);
  float*  cbuf  = (float*) (ws + OFF_CBUF);
  float*  dbuf  = (float*) (ws + OFF_DBUF);
  float*  guid  = (float*) (ws + OFF_GUID);
  float*  Wff   = (float*) (ws + OFF_WF);
  ushort* qb    = (ushort*)(ws + OFF_Z1);
  ushort* kb    = (ushort*)(ws + OFF_Z2);
  ushort* vb    = (ushort*)(ws + OFF_Z3);
  ushort* attnb = (ushort*)(ws + OFF_Z4);
  float*  x0pre = (float*) (ws + OFF_Z1);
  float*  x1f   = (float*) (ws + OFF_Z3);
  ushort* ffnb  = (ushort*)(ws + OFF_M);
  ushort* mid   = (ushort*)(ws + OFF_M + (4u<<20));
  float*  x2pre = (float*) (ws + OFF_Z1);
  ushort* abf   = (ushort*)(ws + OFF_Z4);
  ushort* qtb   = (ushort*)(ws + OFF_Z3);
  ushort* Ubf   = (ushort*)(ws + OFF_M);
  float*  outb  = (float*)d_out;
  float*  out_h = outb + (out_size - 4096);

  static int attr_done = 0;
  if(!attr_done){
    hipFuncSetAttribute((const void*)scan_kernel,
                        hipFuncAttributeMaxDynamicSharedMemorySize, SCAN_DYN_LDS);
    attr_done = 1;
  }

  hipMemsetAsync(flags, 0, 2048, stream);

  // ===== parallel prefix =====
  gemm_kernel<1,0><<<512, 256, 0, stream>>>(x, sa_wq, 256, sa_bq, nullptr, nullptr, qb, 8192,256,256, 1.0f);
  gemm_kernel<1,0><<<512, 256, 0, stream>>>(x, sa_wk, 256, sa_bk, nullptr, nullptr, kb, 8192,256,256, 1.0f);
  gemm_kernel<1,0><<<512, 256, 0, stream>>>(x, sa_wv, 256, sa_bv, nullptr, nullptr, vb, 8192,256,256, 1.0f);
  attn_kernel<<<2048, 256, 0, stream>>>(qb, kb, vb, attnb);
  gemm_kernel<0,0><<<512, 256, 0, stream>>>(attnb, sa_wo, 256, sa_bo, x, x0pre, nullptr, 8192,256,256, 1.0f);
  ln_kernel<<<2048, 256, 0, stream>>>(x0pre, ln1_g, ln1_b, x1f, nullptr);
  guid_kernel<<<16, 256, 0, stream>>>(h0, sp_w, sp_b, guid);
  ffnin_kernel<<<1024, 256, 0, stream>>>(x1f, guid, ffnb);
  gemm_kernel<0,1><<<1024, 256, 0, stream>>>(ffnb, f_w1, 1024, f_b1, nullptr, nullptr, mid, 8192,512,256, 1.0f);
  gemm_kernel<0,0><<<512, 256, 0, stream>>>(mid, f_w2, 256, f_b2, x1f, x2pre, nullptr, 8192,256,512, 1.0f);
  gemm_kernel<0,1><<<1024, 256, 0, stream>>>(ffnb, f_w1 + 512, 1024, f_b1 + 512, nullptr, nullptr, mid, 8192,512,256, 1.0f);
  gemm_kernel<0,0><<<512, 256, 0, stream>>>(mid, f_w2 + (size_t)512*256, 256, nullptr, x2pre, x2pre, nullptr, 8192,256,512, 1.0f);
  ln_kernel<<<2048, 256, 0, stream>>>(x2pre, ln2_g, ln2_b, outb, nullptr);   // output 0 (f32)

  // ===== scan precompute (all GEMMs) =====
  gemm_kernel<1,0><<<512, 256, 0, stream>>>(outb, ps_w, 256, ps_b, outb, nullptr, abf, 8192,256,256, 0.3f);
  gemm_kernel<0,0><<<1024, 256, 0, stream>>>(abf, tr_w1, 512, tr_b1, nullptr, nullptr, Ubf, 8192,512,256, 1.0f);
  gemm_kernel<1,0><<<512, 256, 0, stream>>>(outb, ta_wq, 256, ta_bq, nullptr, nullptr, qtb, 8192,256,256, 1.0f);
  gemm_kernel<1,0><<<32, 256, 0, stream>>>(ta_wo, tr_w1 + (size_t)256*512, 512, nullptr, nullptr, Wff, nullptr, 256,512,256, 1.0f);
  bo_kernel<<<1, 512, 0, stream>>>(ta_bo, tr_w1, bo_f);

  // ===== sequential scan (persistent, LDS k/v caches) =====
  scan_kernel<<<96, 512, SCAN_DYN_LDS, stream>>>(qtb, Ubf, Wff, bo_f, cbuf, dbuf, flags,
                                                 ta_wk, ta_wv, ta_bk, ta_bv, tr_w2, tr_b2,
                                                 ln3_g, ln3_b, ln4_g, ln4_b, h0, out_h);
}

// Round 9
// 4932.867 us; speedup vs baseline: 1.2585x; 1.1854x over previous
//
#include <hip/hip_runtime.h>
#include <hip/hip_bf16.h>

typedef __bf16 bf16x8 __attribute__((ext_vector_type(8)));
typedef float f32x4 __attribute__((ext_vector_type(4)));

__device__ __forceinline__ float b2f(ushort u){
  union { uint u; float f; } x; x.u = ((uint)u) << 16; return x.f;
}
__device__ __forceinline__ ushort f2b(float f){
  union { float f; uint u; } x; x.f = f;
  uint r = x.u + 0x7fff + ((x.u >> 16) & 1);
  return (ushort)(r >> 16);
}
__device__ __forceinline__ uint pack_bf2(float a, float b){
  return (uint)f2b(a) | ((uint)f2b(b) << 16);
}
__device__ __forceinline__ float lo16(uint u){ union{uint a;float f;}x; x.a=u<<16; return x.f; }
__device__ __forceinline__ float hi16(uint u){ union{uint a;float f;}x; x.a=u&0xffff0000u; return x.f; }
__device__ __forceinline__ float gelu_exact(float v){
  return 0.5f * v * (1.0f + erff(v * 0.70710678118654752f));
}

// ---------------------------------------------------------------------------
// 64x64-tile MFMA bf16 GEMM (unchanged)
// ---------------------------------------------------------------------------
template<int AF32, int ACT>
__global__ __launch_bounds__(256) void gemm_kernel(
    const void* __restrict__ Av, const float* __restrict__ W, int ldw,
    const float* __restrict__ bias, const float* residf,
    float* Cf, ushort* Cb,
    int M, int N, int K, float scale)
{
  __shared__ __align__(16) ushort Al[64*40];
  __shared__ __align__(16) ushort Bl[64*40];
  const int nb = N >> 6;
  const int rb = blockIdx.x / nb, cb = blockIdx.x % nb;
  const int tid = threadIdx.x;
  const int w = tid >> 6, l = tid & 63;
  f32x4 acc[4];
#pragma unroll
  for(int i=0;i<4;i++) acc[i] = (f32x4){0.f,0.f,0.f,0.f};
  const int ar = tid >> 2, ai = (tid & 3) << 3;
  const int bk = tid >> 3, bn = (tid & 7) << 3;
  for(int kb = 0; kb < K; kb += 32){
    uint4 au;
    if(AF32){
      const float* Ap = (const float*)Av + (size_t)(rb*64 + ar)*K + kb + ai;
      float4 f0 = *(const float4*)Ap;
      float4 f1 = *(const float4*)(Ap + 4);
      au.x = pack_bf2(f0.x,f0.y); au.y = pack_bf2(f0.z,f0.w);
      au.z = pack_bf2(f1.x,f1.y); au.w = pack_bf2(f1.z,f1.w);
    } else {
      au = *(const uint4*)((const ushort*)Av + (size_t)(rb*64 + ar)*K + kb + ai);
    }
    const float* Wp = W + (size_t)(kb + bk)*ldw + cb*64 + bn;
    float4 w0 = *(const float4*)Wp;
    float4 w1 = *(const float4*)(Wp + 4);
    ushort bs[8];
    bs[0]=f2b(w0.x); bs[1]=f2b(w0.y); bs[2]=f2b(w0.z); bs[3]=f2b(w0.w);
    bs[4]=f2b(w1.x); bs[5]=f2b(w1.y); bs[6]=f2b(w1.z); bs[7]=f2b(w1.w);
    __syncthreads();
    *(uint4*)&Al[ar*40 + ai] = au;
#pragma unroll
    for(int i=0;i<8;i++) Bl[(bn+i)*40 + bk] = bs[i];
    __syncthreads();
    bf16x8 af = *(const bf16x8*)&Al[(w*16 + (l&15))*40 + (l>>4)*8];
#pragma unroll
    for(int c4=0;c4<4;c4++){
      bf16x8 bfv = *(const bf16x8*)&Bl[(c4*16 + (l&15))*40 + (l>>4)*8];
      acc[c4] = __builtin_amdgcn_mfma_f32_16x16x32_bf16(af, bfv, acc[c4], 0,0,0);
    }
  }
#pragma unroll
  for(int c4=0;c4<4;c4++){
#pragma unroll
    for(int r=0;r<4;r++){
      int row = rb*64 + w*16 + (l>>4)*4 + r;
      int col = cb*64 + c4*16 + (l&15);
      size_t idx = (size_t)row*N + col;
      float vv = acc[c4][r];
      if(bias) vv += bias[col];
      vv *= scale;
      if(residf) vv += residf[idx];
      if(ACT) vv = gelu_exact(vv);
      if(Cf) Cf[idx] = vv;
      if(Cb) Cb[idx] = f2b(vv);
    }
  }
}

// ---------------------------------------------------------------------------
// Causal self-attention (unchanged)
// ---------------------------------------------------------------------------
__global__ __launch_bounds__(256) void attn_kernel(const ushort* __restrict__ Q,
    const ushort* __restrict__ K, const ushort* __restrict__ V, ushort* __restrict__ O)
{
  __shared__ float s[16*520];
  __shared__ float kt[64*66];
  __shared__ float rowm[16], rowr[16], redx[256];
  const int bid = blockIdx.x;
  const int qb = bid & 31, h = (bid>>5)&3, b = bid>>7;
  const int tid = threadIdx.x;
  const int qi = tid >> 4, jj = tid & 15;
  const int qrow = qb*16 + qi;
  float qreg[64];
  {
    const ushort* qp = Q + ((size_t)(b*512 + qrow))*256 + h*64;
#pragma unroll
    for(int d=0; d<64; d++) qreg[d] = b2f(qp[d])*0.125f;
  }
  const int ntile = (qb*16 + 79) >> 6;
  for(int jt=0; jt<ntile; jt++){
    {
      int jr = tid >> 2, d0 = (tid & 3) << 4;
      const ushort* kp = K + ((size_t)(b*512 + jt*64 + jr))*256 + h*64 + d0;
#pragma unroll
      for(int i=0;i<16;i++) kt[jr*66 + d0 + i] = b2f(kp[i]);
    }
    __syncthreads();
#pragma unroll
    for(int jl=0;jl<4;jl++){
      int jloc = jj*4 + jl;
      int j = jt*64 + jloc;
      float a = 0.f;
#pragma unroll
      for(int d=0; d<64; d++) a += qreg[d]*kt[jloc*66 + d];
      s[qi*520 + j] = (j <= qrow) ? a : -1e30f;
    }
    __syncthreads();
  }
  const int nj = ntile*64;
  float m = -1e30f;
  for(int j=jj; j<nj; j+=16) m = fmaxf(m, s[qi*520 + j]);
  redx[jj*16 + qi] = m;
  __syncthreads();
  if(tid < 16){
    float mm = -1e30f;
#pragma unroll
    for(int k2=0;k2<16;k2++) mm = fmaxf(mm, redx[k2*16 + tid]);
    rowm[tid] = mm;
  }
  __syncthreads();
  float mrow = rowm[qi];
  float ssum = 0.f;
  for(int j=jj; j<nj; j+=16){
    float e = __expf(s[qi*520+j] - mrow);
    s[qi*520+j] = e; ssum += e;
  }
  redx[jj*16 + qi] = ssum;
  __syncthreads();
  if(tid < 16){
    float t2 = 0.f;
#pragma unroll
    for(int k2=0;k2<16;k2++) t2 += redx[k2*16 + tid];
    rowr[tid] = 1.0f/t2;
  }
  const int dd = jj;
  float acc4[4] = {0,0,0,0};
  for(int jt=0; jt<ntile; jt++){
    __syncthreads();
    {
      int jr = tid >> 2, d0 = (tid & 3) << 4;
      const ushort* vp = V + ((size_t)(b*512 + jt*64 + jr))*256 + h*64 + d0;
#pragma unroll
      for(int i=0;i<16;i++) kt[jr*66 + d0 + i] = b2f(vp[i]);
    }
    __syncthreads();
#pragma unroll
    for(int jl=0;jl<64;jl++){
      float p = s[qi*520 + jt*64 + jl];
#pragma unroll
      for(int i=0;i<4;i++) acc4[i] += p*kt[jl*66 + dd*4 + i];
    }
  }
  float rr = rowr[qi];
  ushort* op = O + ((size_t)(b*512 + qrow))*256 + h*64 + dd*4;
#pragma unroll
  for(int i=0;i<4;i++) op[i] = f2b(acc4[i]*rr);
}

// ---------------------------------------------------------------------------
// LayerNorm / small kernels (unchanged)
// ---------------------------------------------------------------------------
__global__ __launch_bounds__(256) void ln_kernel(const float* __restrict__ in,
    const float* __restrict__ g, const float* __restrict__ be,
    float* outf, ushort* outb)
{
  int row = blockIdx.x*4 + (threadIdx.x>>6);
  int lane = threadIdx.x & 63;
  size_t idx = (size_t)row*256 + lane*4;
  float4 v = *(const float4*)(in + idx);
  float s1 = v.x+v.y+v.z+v.w;
  float s2 = v.x*v.x + v.y*v.y + v.z*v.z + v.w*v.w;
#pragma unroll
  for(int off=32; off; off>>=1){ s1 += __shfl_xor(s1,off); s2 += __shfl_xor(s2,off); }
  float mu = s1*(1.f/256.f);
  float var = s2*(1.f/256.f) - mu*mu;
  float r = rsqrtf(var + 1e-5f);
  float vals[4] = {v.x,v.y,v.z,v.w};
  float4 o4; ushort4 ob;
  float* oo = (float*)&o4; ushort* obp = (ushort*)&ob;
#pragma unroll
  for(int i=0;i<4;i++){
    int d = lane*4 + i;
    float y = (vals[i]-mu)*r*g[d] + be[d];
    oo[i] = y; obp[i] = f2b(y);
  }
  if(outf) *(float4*)(outf+idx) = o4;
  if(outb) *(ushort4*)(outb+idx) = ob;
}

__global__ void guid_kernel(const float* __restrict__ h0, const float* __restrict__ spw,
                            const float* __restrict__ spb, float* __restrict__ guid)
{
  int b = blockIdx.x, c = threadIdx.x;
  float s = spb[c];
  for(int r=0;r<256;r++) s += h0[b*256+r]*spw[r*256+c];
  guid[b*256+c] = s;
}

__global__ void ffnin_kernel(const float* __restrict__ x1, const float* __restrict__ guid,
                             ushort* __restrict__ out)
{
  size_t base = ((size_t)blockIdx.x*256 + threadIdx.x)*8;
  int row = (int)(base >> 8); int bb = row >> 9; int c = (int)(base & 255);
  float4 v0 = *(const float4*)(x1 + base);
  float4 v1 = *(const float4*)(x1 + base + 4);
  const float* gp = guid + bb*256 + c;
  const float* xs = (const float*)&v0;
  ushort o[8];
#pragma unroll
  for(int i=0;i<4;i++) o[i] = f2b(xs[i] + 0.3f*gp[i]);
  const float* xs1 = (const float*)&v1;
#pragma unroll
  for(int i=0;i<4;i++) o[4+i] = f2b(xs1[i] + 0.3f*gp[4+i]);
  *(uint4*)(out + base) = *(uint4*)o;
}

__global__ void bo_kernel(const float* __restrict__ ta_bo, const float* __restrict__ tr_w1,
                          float* __restrict__ bo_f)
{
  int c = threadIdx.x;
  float s = 0.f;
  for(int m=0;m<256;m++) s += ta_bo[m]*tr_w1[(size_t)(256+m)*512 + c];
  bo_f[c] = s;
}

// ---------------------------------------------------------------------------
// Persistent scan. 128 blocks x 512 threads. Dynamic LDS 132 KB (X k/v caches).
// role = bid>>4: 0..3 = X (attention head), 4..7 = Y (MLP quarter-shard, 128 hid).
// All matvecs use shfl-pair reduction with bank-staggered 8i+2s row interleave
// (no LDS reduce barriers, no register spills: Y = 64 packed weight regs).
// X: 4 barriers/step; single-wave LN3 (wave0 holds h in regs).
// Y: 3 barriers/step; per-lane flag polling.
// Flags: [0..63] fastX(b*4+hd)=t, [64..127] fastY(b*4+ish)=t+1,
//        [128..191] shadowX, [192..255] shadowY, [256..383] xcc table.
// ---------------------------------------------------------------------------
__global__ __launch_bounds__(512, 1) void scan_kernel(
    const ushort* __restrict__ qtb, const ushort* __restrict__ Ubf,
    const float* __restrict__ Wf, const float* __restrict__ bo_f,
    float* cbuf, float* dbuf, int* flags,
    const float* __restrict__ ta_wk, const float* __restrict__ ta_wv,
    const float* __restrict__ ta_bk, const float* __restrict__ ta_bv,
    const float* __restrict__ tr_w2, const float* __restrict__ tr_b2,
    const float* __restrict__ ln3_g, const float* __restrict__ ln3_b,
    const float* __restrict__ ln4_g, const float* __restrict__ ln4_b,
    const float* __restrict__ h0, float* __restrict__ out_h)
{
  __shared__ __align__(16) float red[1024];
  __shared__ float pbuf[512];
  __shared__ __align__(16) float hbuf[256];
  __shared__ float ctxL[256];
  __shared__ float qbufS[64];
  __shared__ float misc[16];
  __shared__ float glbuf[128];
  __shared__ int cp_same[4];
  extern __shared__ __align__(16) ushort dynL[];
  ushort* kcL = dynL;             // [512][66] u16
  ushort* vcL = dynL + 512*66;    // [512][66] u16

  const int tid = threadIdx.x;
  const int bid = blockIdx.x;
  const int b = bid & 15;
  const int role = bid >> 4;

  if(role < 4){   // zero k/v caches (tail reads must see 0.0)
    for(int i = tid; i < 512*66; i += 512){ kcL[i] = 0; vcL[i] = 0; }
  }

  // ---- one-time XCD handshake ----
  int myxcc;
  asm volatile("s_getreg_b32 %0, hwreg(HW_REG_XCC_ID)" : "=s"(myxcc));
  if(tid == 0)
    __hip_atomic_store(&flags[256 + bid], myxcc + 1, __ATOMIC_RELEASE, __HIP_MEMORY_SCOPE_AGENT);
  if(tid < 4){
    int cbid = (role < 4) ? (64 + tid*16 + b) : (tid*16 + b);
    int v;
    while((v = __hip_atomic_load(&flags[256 + cbid], __ATOMIC_ACQUIRE, __HIP_MEMORY_SCOPE_AGENT)) == 0)
      __builtin_amdgcn_s_sleep(8);
    cp_same[tid] = ((v - 1) == myxcc);
  }
  __syncthreads();
  const int anyrem = !(cp_same[0] && cp_same[1] && cp_same[2] && cp_same[3]);

  if(role < 4){
    // ================= X: attention head hd =================
    const int hd = role;
    const int bh = b*4 + hd;
    // matvec: thread = out*4 + s; out<64 -> k col, out>=64 -> v col.
    const int out = tid >> 2, sX = tid & 3;
    const int kvSel = out >> 6, colX = out & 63;
    const float* WX = kvSel ? ta_wv : ta_wk;
    uint wp[32];
#pragma unroll
    for(int i=0;i<32;i++){
      int r0 = 8*i + 2*sX;
      wp[i] = pack_bf2(WX[(size_t)r0*256 + hd*64 + colX],
                       WX[(size_t)(r0+1)*256 + hd*64 + colX]);
    }
    const float pbX = kvSel ? ta_bv[hd*64 + colX] : ta_bk[hd*64 + colX];
    // wave0 LN state (lane l owns cols 4l..4l+3)
    float h4[4], b2r4[4], g34[4], b34[4];
    if(tid < 64){
#pragma unroll
      for(int c=0;c<4;c++){
        int d = 4*tid + c;
        h4[c] = h0[b*256 + d]; b2r4[c] = tr_b2[d]; g34[c] = ln3_g[d]; b34[c] = ln3_b[d];
      }
      *(float4*)&hbuf[4*tid] = *(float4*)h4;
    }
    __syncthreads();

#pragma clang loop unroll(disable)
    for(int t=0;t<512;t++){
      if(t > 0){
        ushort qpre = 0;
        if(tid >= 448) qpre = qtb[((size_t)(b*512 + t))*256 + hd*64 + (tid - 448)];
        // k/v matvec (shfl-pair over 4 threads)
        float acc = 0.f;
#pragma unroll
        for(int i=0;i<32;i++){
          int r0 = 8*i + 2*sX;
          acc += hbuf[r0]*lo16(wp[i]) + hbuf[r0+1]*hi16(wp[i]);
        }
        acc += __shfl_xor(acc, 1);
        acc += __shfl_xor(acc, 2);
        if(sX == 0){
          ushort u = f2b(acc + pbX);
          if(kvSel == 0) kcL[(t-1)*66 + colX] = u;
          else           vcL[(t-1)*66 + colX] = u;
        }
        if(tid >= 448) qbufS[tid - 448] = b2f(qpre)*0.125f;
        __syncthreads();                                   // B_cache
        // scores j<t + per-wave online softmax
        const int j = tid;
        float sc = -3.0e38f;
        if(j < t){
          const uint* kr = (const uint*)(kcL + j*66);
          float a = 0.f;
#pragma unroll
          for(int w=0; w<32; w++){
            uint kk = kr[w];
            a += qbufS[2*w]   * lo16(kk);
            a += qbufS[2*w+1] * hi16(kk);
          }
          sc = a;
        }
        float wm = sc;
#pragma unroll
        for(int off=32; off; off>>=1) wm = fmaxf(wm, __shfl_xor(wm, off));
        float e = (j < t) ? __expf(sc - wm) : 0.f;
        float ws = e;
#pragma unroll
        for(int off=32; off; off>>=1) ws += __shfl_xor(ws, off);
        pbuf[j] = e;
        if((tid&63)==0){ misc[tid>>6] = wm; misc[8 + (tid>>6)] = ws; }
        __syncthreads();                                   // B_soft
        float gm = misc[0];
#pragma unroll
        for(int i=1;i<8;i++) gm = fmaxf(gm, misc[i]);
        float gsum = 0.f;
#pragma unroll
        for(int i=0;i<8;i++) gsum += misc[8+i]*__expf(misc[i]-gm);
        float rsum = 1.0f / gsum;
        // ctx: group g (16 groups of 32 j), lane l handles d-pair (2l,2l+1)
        {
          const int g = tid >> 5, l = tid & 31;
          float sfac = __expf(misc[g>>1] - gm);
          float a0 = 0.f, a1 = 0.f;
          const uint* vbase = (const uint*)vcL;
#pragma unroll
          for(int i=0;i<32;i++){
            int j2 = g*32 + i;
            uint vv = vbase[j2*33 + l];
            float p = pbuf[j2];
            a0 += p*lo16(vv); a1 += p*hi16(vv);
          }
          float2 pr; pr.x = a0*sfac; pr.y = a1*sfac;
          *(float2*)&red[g*64 + 2*l] = pr;
        }
        __syncthreads();                                   // B_ctx
        if(tid < 64){                                      // wave 0 only
          float cv = 0.f;
#pragma unroll
          for(int g2=0;g2<16;g2++) cv += red[g2*64 + tid];
          cbuf[b*256 + hd*64 + tid] = cv*rsum;
          asm volatile("s_waitcnt vmcnt(0)" ::: "memory");
          if(tid==0){
            *(volatile int*)&flags[bh] = t;
            if(anyrem)
              __hip_atomic_store(&flags[128 + bh], t, __ATOMIC_RELEASE, __HIP_MEMORY_SCOPE_AGENT);
          }
        }
      } // t>0

      // wave0: poll 4 Y deltas, then single-wave LN3
      if(tid < 4){
        if(cp_same[tid]){
          while(*(volatile int*)&flags[64 + b*4 + tid] < t+1) __builtin_amdgcn_s_sleep(1);
        } else {
          while(__hip_atomic_load(&flags[192 + b*4 + tid], __ATOMIC_RELAXED, __HIP_MEMORY_SCOPE_AGENT) < t+1)
            __builtin_amdgcn_s_sleep(2);
        }
      }
      if(tid < 64){
        if(anyrem) __builtin_amdgcn_fence(__ATOMIC_ACQUIRE, "agent");
        float ds[4] = {0.f,0.f,0.f,0.f};
#pragma unroll
        for(int i=0;i<4;i++){
#pragma unroll
          for(int c=0;c<4;c++)
            ds[c] += *(volatile float*)&dbuf[(b*4+i)*256 + 4*tid + c];
        }
        float v4[4]; float s1 = 0.f, s2 = 0.f;
#pragma unroll
        for(int c=0;c<4;c++){
          v4[c] = h4[c] + 0.5f*(ds[c] + b2r4[c]);
          s1 += v4[c]; s2 += v4[c]*v4[c];
        }
#pragma unroll
        for(int off=32; off; off>>=1){ s1 += __shfl_xor(s1,off); s2 += __shfl_xor(s2,off); }
        float mu = s1*(1.f/256.f);
        float qq = s2*(1.f/256.f) - mu*mu;
        float rstd = rsqrtf(qq + 1e-5f);
#pragma unroll
        for(int c=0;c<4;c++) h4[c] = (v4[c]-mu)*rstd*g34[c] + b34[c];
        *(float4*)&hbuf[4*tid] = *(float4*)h4;
      }
      __syncthreads();                                     // B_LN
    } // t loop

    if(hd == 0 && tid < 64){
      float s1 = 0.f, s2 = 0.f;
#pragma unroll
      for(int c=0;c<4;c++){ s1 += h4[c]; s2 += h4[c]*h4[c]; }
#pragma unroll
      for(int off=32; off; off>>=1){ s1 += __shfl_xor(s1,off); s2 += __shfl_xor(s2,off); }
      float mu = s1*(1.f/256.f);
      float qq = s2*(1.f/256.f) - mu*mu;
      float rstd = rsqrtf(qq + 1e-5f);
#pragma unroll
      for(int c=0;c<4;c++){
        int d = 4*tid + c;
        out_h[b*256 + d] = (h4[c]-mu)*rstd*ln4_g[d] + ln4_b[d];
      }
    }
  } else {
    // ================= Y: MLP quarter-shard ish (128 hidden) =================
    const int ish = role - 4;
    // Wf matvec: thread = hid*4 + sY (hid<128)
    const int hid = tid >> 2, sY = tid & 3;
    const int colY = ish*128 + hid;
    uint wfp[32];
#pragma unroll
    for(int i=0;i<32;i++){
      int r0 = 8*i + 2*sY;
      wfp[i] = pack_bf2(Wf[(size_t)r0*512 + colY], Wf[(size_t)(r0+1)*512 + colY]);
    }
    // w2 matvec: thread = dcol*2 + s2 (dcol<256), local hidden rows 4i+2*s2
    const int dcol = tid >> 1, s2 = tid & 1;
    uint w2p[32];
#pragma unroll
    for(int i=0;i<32;i++){
      int r0 = ish*128 + 4*i + 2*s2;
      w2p[i] = pack_bf2(tr_w2[(size_t)r0*256 + dcol], tr_w2[(size_t)(r0+1)*256 + dcol]);
    }
    const float borr = (sY==0) ? bo_f[colY] : 0.f;
    __syncthreads();

#pragma clang loop unroll(disable)
    for(int t=0;t<512;t++){
      ushort uvs = 0;
      if(sY == 0) uvs = Ubf[((size_t)(b*512 + t))*512 + colY];
      if(t > 0){
        if(tid < 256){
          int q = tid >> 6;
          if(cp_same[q]){
            while(*(volatile int*)&flags[b*4 + q] < t) __builtin_amdgcn_s_sleep(1);
          } else {
            while(__hip_atomic_load(&flags[128 + b*4 + q], __ATOMIC_RELAXED, __HIP_MEMORY_SCOPE_AGENT) < t)
              __builtin_amdgcn_s_sleep(2);
          }
        }
        if(anyrem) __builtin_amdgcn_fence(__ATOMIC_ACQUIRE, "agent");
        if(tid < 256) ctxL[tid] = *(volatile float*)&cbuf[b*256 + tid];
      }
      __syncthreads();                                     // B1
      float accf = 0.f;
      if(t > 0){
#pragma unroll
        for(int i=0;i<32;i++){
          int r0 = 8*i + 2*sY;
          accf += ctxL[r0]*lo16(wfp[i]) + ctxL[r0+1]*hi16(wfp[i]);
        }
        accf += __shfl_xor(accf, 1);
        accf += __shfl_xor(accf, 2);
      }
      if(sY == 0){
        float g1 = b2f(uvs) + ((t>0) ? (borr + accf) : 0.f);
        glbuf[hid] = gelu_exact(g1);
      }
      __syncthreads();                                     // B2
      {
        float dp = 0.f;
#pragma unroll
        for(int i=0;i<32;i++){
          int r0 = 4*i + 2*s2;
          dp += glbuf[r0]*lo16(w2p[i]) + glbuf[r0+1]*hi16(w2p[i]);
        }
        dp += __shfl_xor(dp, 1);
        if(s2 == 0) dbuf[(b*4+ish)*256 + dcol] = dp;
      }
      asm volatile("s_waitcnt vmcnt(0)" ::: "memory");
      __syncthreads();                                     // B3
      if(tid == 0){
        *(volatile int*)&flags[64 + b*4 + ish] = t+1;
        if(anyrem)
          __hip_atomic_store(&flags[192 + b*4 + ish], t+1, __ATOMIC_RELEASE, __HIP_MEMORY_SCOPE_AGENT);
      }
    }
  }
}

// ---------------------------------------------------------------------------
// Workspace layout (bytes). TOTAL = 29 MiB.
// ---------------------------------------------------------------------------
#define OFF_FLAGS ((size_t)0)
#define OFF_BOF   ((size_t)2048)
#define OFF_CBUF  ((size_t)4096)
#define OFF_DBUF  ((size_t)20480)
#define OFF_GUID  ((size_t)86016)
#define OFF_WF    ((size_t)131072)
#define OFF_Z1    ((size_t)(1u<<20))
#define OFF_Z2    ((size_t)(5u<<20))
#define OFF_Z3    ((size_t)(9u<<20))
#define OFF_Z4    ((size_t)(13u<<20))
#define OFF_M     ((size_t)(17u<<20))

#define SCAN_DYN_LDS (512*66*2*2)   // 135168 B

extern "C" void kernel_launch(void* const* d_in, const int* in_sizes, int n_in,
                              void* d_out, int out_size, void* d_ws, size_t ws_size,
                              hipStream_t stream)
{
  const float* x     = (const float*)d_in[0];
  const float* h0    = (const float*)d_in[1];
  const float* sa_wq = (const float*)d_in[2];
  const float* sa_wk = (const float*)d_in[3];
  const float* sa_wv = (const float*)d_in[4];
  const float* sa_wo = (const float*)d_in[5];
  const float* sa_bq = (const float*)d_in[6];
  const float* sa_bk = (const float*)d_in[7];
  const float* sa_bv = (const float*)d_in[8];
  const float* sa_bo = (const float*)d_in[9];
  const float* f_w1  = (const float*)d_in[10];
  const float* f_b1  = (const float*)d_in[11];
  const float* f_w2  = (const float*)d_in[12];
  const float* f_b2  = (const float*)d_in[13];
  const float* ta_wq = (const float*)d_in[14];
  const float* ta_wk = (const float*)d_in[15];
  const float* ta_wv = (const float*)d_in[16];
  const float* ta_wo = (const float*)d_in[17];
  const float* ta_bq = (const float*)d_in[18];
  const float* ta_bk = (const float*)d_in[19];
  const float* ta_bv = (const float*)d_in[20];
  const float* ta_bo = (const float*)d_in[21];
  const float* tr_w1 = (const float*)d_in[22];
  const float* tr_b1 = (const float*)d_in[23];
  const float* tr_w2 = (const float*)d_in[24];
  const float* tr_b2 = (const float*)d_in[25];
  const float* ps_w  = (const float*)d_in[26];
  const float* ps_b  = (const float*)d_in[27];
  const float* sp_w  = (const float*)d_in[28];
  const float* sp_b  = (const float*)d_in[29];
  const float* ln1_g = (const float*)d_in[30];
  const float* ln1_b = (const float*)d_in[31];
  const float* ln2_g = (const float*)d_in[32];
  const float* ln2_b = (const float*)d_in[33];
  const float* ln3_g = (const float*)d_in[34];
  const float* ln3_b = (const float*)d_in[35];
  const float* ln4_g = (const float*)d_in[36];
  const float* ln4_b = (const float*)d_in[37];

  char* ws = (char*)d_ws;
  int*    flags = (int*)   (ws + OFF_FLAGS);
  float*  bo_f  = (float*) (ws + OFF_BOF);
  float*  cbuf  = (float*) (ws + OFF_CBUF);
  float*  dbuf  = (float*) (ws + OFF_DBUF);
  float*  guid  = (float*) (ws + OFF_GUID);
  float*  Wff   = (float*) (ws + OFF_WF);
  ushort* qb    = (ushort*)(ws + OFF_Z1);
  ushort* kb    = (ushort*)(ws + OFF_Z2);
  ushort* vb    = (ushort*)(ws + OFF_Z3);
  ushort* attnb = (ushort*)(ws + OFF_Z4);
  float*  x0pre = (float*) (ws + OFF_Z1);
  float*  x1f   = (float*) (ws + OFF_Z3);
  ushort* ffnb  = (ushort*)(ws + OFF_M);
  ushort* mid   = (ushort*)(ws + OFF_M + (4u<<20));
  float*  x2pre = (float*) (ws + OFF_Z1);
  ushort* abf   = (ushort*)(ws + OFF_Z4);
  ushort* qtb   = (ushort*)(ws + OFF_Z3);
  ushort* Ubf   = (ushort*)(ws + OFF_M);
  float*  outb  = (float*)d_out;
  float*  out_h = outb + (out_size - 4096);

  static int attr_done = 0;
  if(!attr_done){
    hipFuncSetAttribute((const void*)scan_kernel,
                        hipFuncAttributeMaxDynamicSharedMemorySize, SCAN_DYN_LDS);
    attr_done = 1;
  }

  hipMemsetAsync(flags, 0, 2048, stream);

  // ===== parallel prefix =====
  gemm_kernel<1,0><<<512, 256, 0, stream>>>(x, sa_wq, 256, sa_bq, nullptr, nullptr, qb, 8192,256,256, 1.0f);
  gemm_kernel<1,0><<<512, 256, 0, stream>>>(x, sa_wk, 256, sa_bk, nullptr, nullptr, kb, 8192,256,256, 1.0f);
  gemm_kernel<1,0><<<512, 256, 0, stream>>>(x, sa_wv, 256, sa_bv, nullptr, nullptr, vb, 8192,256,256, 1.0f);
  attn_kernel<<<2048, 256, 0, stream>>>(qb, kb, vb, attnb);
  gemm_kernel<0,0><<<512, 256, 0, stream>>>(attnb, sa_wo, 256, sa_bo, x, x0pre, nullptr, 8192,256,256, 1.0f);
  ln_kernel<<<2048, 256, 0, stream>>>(x0pre, ln1_g, ln1_b, x1f, nullptr);
  guid_kernel<<<16, 256, 0, stream>>>(h0, sp_w, sp_b, guid);
  ffnin_kernel<<<1024, 256, 0, stream>>>(x1f, guid, ffnb);
  gemm_kernel<0,1><<<1024, 256, 0, stream>>>(ffnb, f_w1, 1024, f_b1, nullptr, nullptr, mid, 8192,512,256, 1.0f);
  gemm_kernel<0,0><<<512, 256, 0, stream>>>(mid, f_w2, 256, f_b2, x1f, x2pre, nullptr, 8192,256,512, 1.0f);
  gemm_kernel<0,1><<<1024, 256, 0, stream>>>(ffnb, f_w1 + 512, 1024, f_b1 + 512, nullptr, nullptr, mid, 8192,512,256, 1.0f);
  gemm_kernel<0,0><<<512, 256, 0, stream>>>(mid, f_w2 + (size_t)512*256, 256, nullptr, x2pre, x2pre, nullptr, 8192,256,512, 1.0f);
  ln_kernel<<<2048, 256, 0, stream>>>(x2pre, ln2_g, ln2_b, outb, nullptr);   // output 0 (f32)

  // ===== scan precompute (all GEMMs) =====
  gemm_kernel<1,0><<<512, 256, 0, stream>>>(outb, ps_w, 256, ps_b, outb, nullptr, abf, 8192,256,256, 0.3f);
  gemm_kernel<0,0><<<1024, 256, 0, stream>>>(abf, tr_w1, 512, tr_b1, nullptr, nullptr, Ubf, 8192,512,256, 1.0f);
  gemm_kernel<1,0><<<512, 256, 0, stream>>>(outb, ta_wq, 256, ta_bq, nullptr, nullptr, qtb, 8192,256,256, 1.0f);
  gemm_kernel<1,0><<<32, 256, 0, stream>>>(ta_wo, tr_w1 + (size_t)256*512, 512, nullptr, nullptr, Wff, nullptr, 256,512,256, 1.0f);
  bo_kernel<<<1, 512, 0, stream>>>(ta_bo, tr_w1, bo_f);

  // ===== sequential scan (persistent, LDS k/v caches, no spills) =====
  scan_kernel<<<128, 512, SCAN_DYN_LDS, stream>>>(qtb, Ubf, Wff, bo_f, cbuf, dbuf, flags,
                                                  ta_wk, ta_wv, ta_bk, ta_bv, tr_w2, tr_b2,
                                                  ln3_g, ln3_b, ln4_g, ln4_b, h0, out_h);
}